// Round 1
// baseline (377.901 us; speedup 1.0000x reference)
//
#include <hip/hip_runtime.h>
#include <math.h>

#define NF 32
#define NN 4096
#define ND 64
#define NK 512

// loss = (q_latent + 0.25 * e_latent) = 1.25 * mean((q - x)^2)
#define LOSS_SCALE (1.25f / (float)(NF * NN * ND))

__global__ void vq_zero_loss(float* __restrict__ loss_slot) {
    if (threadIdx.x == 0) *loss_slot = 0.0f;
}

__global__ __launch_bounds__(256, 4)
void vq_main(const float* __restrict__ x_in, const float* __restrict__ w,
             float* __restrict__ out) {
    const int f = blockIdx.y;
    const int n = blockIdx.x * 256 + threadIdx.x;

    const float* __restrict__ wf = w + (size_t)f * (ND * NK);
    const float* __restrict__ xr = x_in + ((size_t)f * NN + n) * ND;

    // ---- per-block ||w_k||^2 table in LDS ----
    __shared__ float w2s[NK];
    for (int k = threadIdx.x; k < NK; k += 256) {
        float s = 0.0f;
#pragma unroll
        for (int d = 0; d < ND; ++d) {
            float v = wf[d * NK + k];   // coalesced across threads (consecutive k)
            s = fmaf(v, v, s);
        }
        w2s[k] = s;
    }
    __syncthreads();

    // ---- load this thread's row into registers ----
    float x[ND];
#pragma unroll
    for (int d4 = 0; d4 < ND / 4; ++d4) {
        float4 v = *(const float4*)(xr + 4 * d4);
        x[4 * d4 + 0] = v.x;
        x[4 * d4 + 1] = v.y;
        x[4 * d4 + 2] = v.z;
        x[4 * d4 + 3] = v.w;
    }

    // ---- argmin over K: score = ||w_k||^2 - 2 x.w_k  (||x||^2 omitted: row-constant) ----
    float best = INFINITY;
    int bidx = 0;

    for (int k0 = 0; k0 < NK; k0 += 4) {
        float t0 = 0.0f, t1 = 0.0f, t2 = 0.0f, t3 = 0.0f;
#pragma unroll
        for (int d = 0; d < ND; ++d) {
            // wave-uniform address -> expect s_load_dwordx4 (SMEM broadcast)
            const float4 wv = *(const float4*)(wf + d * NK + k0);
            const float xd = x[d];
            t0 = fmaf(xd, wv.x, t0);
            t1 = fmaf(xd, wv.y, t1);
            t2 = fmaf(xd, wv.z, t2);
            t3 = fmaf(xd, wv.w, t3);
        }
        const float s0 = w2s[k0 + 0] - 2.0f * t0;
        const float s1 = w2s[k0 + 1] - 2.0f * t1;
        const float s2 = w2s[k0 + 2] - 2.0f * t2;
        const float s3 = w2s[k0 + 3] - 2.0f * t3;
        // strict < : first index wins ties, matching jnp.argmin
        if (s0 < best) { best = s0; bidx = k0 + 0; }
        if (s1 < best) { best = s1; bidx = k0 + 1; }
        if (s2 < best) { best = s2; bidx = k0 + 2; }
        if (s3 < best) { best = s3; bidx = k0 + 3; }
    }

    // ---- epilogue: gather codeword, write output, accumulate loss ----
    float lsum = 0.0f;
    float* __restrict__ orow = out + ((size_t)f * NN + n) * ND;
#pragma unroll
    for (int d4 = 0; d4 < ND / 4; ++d4) {
        float4 q;
        q.x = wf[(4 * d4 + 0) * NK + bidx];
        q.y = wf[(4 * d4 + 1) * NK + bidx];
        q.z = wf[(4 * d4 + 2) * NK + bidx];
        q.w = wf[(4 * d4 + 3) * NK + bidx];
        const float dx0 = q.x - x[4 * d4 + 0];
        const float dx1 = q.y - x[4 * d4 + 1];
        const float dx2 = q.z - x[4 * d4 + 2];
        const float dx3 = q.w - x[4 * d4 + 3];
        lsum = fmaf(dx0, dx0, lsum);
        lsum = fmaf(dx1, dx1, lsum);
        lsum = fmaf(dx2, dx2, lsum);
        lsum = fmaf(dx3, dx3, lsum);
        *(float4*)(orow + 4 * d4) = q;   // straight-through: output == quantized
    }

    // wave-level reduction (wave = 64 lanes), one atomic per wave
#pragma unroll
    for (int off = 32; off > 0; off >>= 1) {
        lsum += __shfl_down(lsum, off, 64);
    }
    if ((threadIdx.x & 63) == 0) {
        atomicAdd(out + (size_t)NF * NN * ND, lsum * LOSS_SCALE);
    }
}

extern "C" void kernel_launch(void* const* d_in, const int* in_sizes, int n_in,
                              void* d_out, int out_size, void* d_ws, size_t ws_size,
                              hipStream_t stream) {
    const float* x_in = (const float*)d_in[0];  // [F, N, D] fp32
    const float* w    = (const float*)d_in[1];  // [F, D, K] fp32
    float* out        = (float*)d_out;          // [F*N*D] output then [1] loss

    // d_out is poisoned (0xAA) before every timed launch: zero the loss slot first
    vq_zero_loss<<<1, 64, 0, stream>>>(out + (size_t)NF * NN * ND);

    dim3 grid(NN / 256, NF);
    vq_main<<<grid, 256, 0, stream>>>(x_in, w, out);
}